// Round 8
// baseline (138.388 us; speedup 1.0000x reference)
//
#include <hip/hip_runtime.h>

#define FD 64  // feature dim

typedef __attribute__((ext_vector_type(8))) short bf16x8;
typedef __attribute__((ext_vector_type(4))) float f32x4;
typedef __attribute__((ext_vector_type(4))) unsigned short u16x4;

__device__ inline short f2bf(float f) {   // fp32 -> bf16 RNE
    union { float f; unsigned u; } v; v.f = f;
    unsigned r = (v.u + 0x7fffu + ((v.u >> 16) & 1u)) >> 16;
    return (short)r;
}
__device__ inline float bf2f(unsigned short u) {
    union { unsigned u; float f; } v; v.u = ((unsigned)u) << 16;
    return v.f;
}

// ---------------- deg + position: pos[e] = old count of dst[e] ----------------
__global__ void degpos_kernel(const int* __restrict__ dst, int* __restrict__ degi,
                              unsigned short* __restrict__ pos, int E) {
    int i = blockIdx.x * blockDim.x + threadIdx.x;
    int stride = gridDim.x * blockDim.x;
    for (; i < E; i += stride) {
        pos[i] = (unsigned short)atomicAdd(&degi[dst[i]], 1);
    }
}

// ---------------- Scan (exclusive) of degi -> offs (block-local); dis fused ----------------
#define SCAN_ELEMS 2048  // 256 threads x 8 elements

__global__ void scan1_kernel(const int* __restrict__ degi, int* __restrict__ offs,
                             int* __restrict__ bsums, float* __restrict__ dis, int N) {
    __shared__ int tsum[256];
    int base = blockIdx.x * SCAN_ELEMS + threadIdx.x * 8;
    int v[8];
    int s = 0;
    #pragma unroll
    for (int k = 0; k < 8; ++k) {
        int idx = base + k;
        v[k] = (idx < N) ? degi[idx] : 0;
        if (idx < N) dis[idx] = rsqrtf((float)v[k] + 1.0f);   // fused dis
        s += v[k];
    }
    tsum[threadIdx.x] = s;
    __syncthreads();
    for (int off = 1; off < 256; off <<= 1) {
        int t = (threadIdx.x >= off) ? tsum[threadIdx.x - off] : 0;
        __syncthreads();
        tsum[threadIdx.x] += t;
        __syncthreads();
    }
    int excl = (threadIdx.x == 0) ? 0 : tsum[threadIdx.x - 1];
    #pragma unroll
    for (int k = 0; k < 8; ++k) {
        int idx = base + k;
        if (idx < N) offs[idx] = excl;    // BLOCK-LOCAL exclusive scan
        excl += v[k];
    }
    if (threadIdx.x == 255) bsums[blockIdx.x] = tsum[255];
}

__global__ void scan2_kernel(int* __restrict__ bsums, int nb) {
    __shared__ int t[256];
    int v = (threadIdx.x < nb) ? bsums[threadIdx.x] : 0;
    t[threadIdx.x] = v;
    __syncthreads();
    for (int off = 1; off < 256; off <<= 1) {
        int u = (threadIdx.x >= off) ? t[threadIdx.x - off] : 0;
        __syncthreads();
        t[threadIdx.x] += u;
        __syncthreads();
    }
    if (threadIdx.x < nb) bsums[threadIdx.x] = (threadIdx.x == 0) ? 0 : t[threadIdx.x - 1];
}

// scan3 (fallback path only): materialize global offs
__global__ void scan3_kernel(int* __restrict__ offs, const int* __restrict__ bsums, int N) {
    int i = blockIdx.x * blockDim.x + threadIdx.x;
    if (i < N) offs[i] += bsums[i / SCAN_ELEMS];
}

// ---------------- fill CSR buckets, atomic-free; bsums folded in ----------------
__global__ void fill_pos_kernel(const int* __restrict__ src, const int* __restrict__ dst,
                                const int* __restrict__ offs, const int* __restrict__ bsums,
                                const unsigned short* __restrict__ pos,
                                int* __restrict__ bucket, int E) {
    int i = blockIdx.x * blockDim.x + threadIdx.x;
    int stride = gridDim.x * blockDim.x;
    for (; i < E; i += stride) {
        int d = dst[i];
        bucket[offs[d] + bsums[d >> 11] + (int)pos[i]] = src[i];
    }
}

// ---------------- z = bf16( (x @ W^T) * dis[:,None] ) via MFMA ----------------
__global__ __launch_bounds__(256) void z_mfma_kernel(
        const float* __restrict__ x, const float* __restrict__ dis,
        const float* __restrict__ W, unsigned short* __restrict__ z, int N) {
    int lane = threadIdx.x & 63;
    int r16  = lane & 15;
    int kg   = lane >> 4;   // 0..3

    bf16x8 bfrag[4][2];
    #pragma unroll
    for (int ct = 0; ct < 4; ++ct) {
        #pragma unroll
        for (int kk = 0; kk < 2; ++kk) {
            const float* wp = W + (size_t)(ct * 16 + r16) * FD + kk * 32 + kg * 8;
            float4 w0 = *(const float4*)wp;
            float4 w1 = *(const float4*)(wp + 4);
            bf16x8 b;
            b[0] = f2bf(w0.x); b[1] = f2bf(w0.y); b[2] = f2bf(w0.z); b[3] = f2bf(w0.w);
            b[4] = f2bf(w1.x); b[5] = f2bf(w1.y); b[6] = f2bf(w1.z); b[7] = f2bf(w1.w);
            bfrag[ct][kk] = b;
        }
    }

    int wid    = blockIdx.x * (blockDim.x >> 6) + (threadIdx.x >> 6);
    int nwaves = gridDim.x * (blockDim.x >> 6);
    int tiles  = (N + 15) >> 4;

    for (int t = wid; t < tiles; t += nwaves) {
        int n0  = t << 4;
        int row = n0 + r16;
        int rl  = row < N ? row : N - 1;          // clamp: extra rows never stored
        const float* xp = x + (size_t)rl * FD + kg * 8;
        float4 a00 = *(const float4*)(xp);
        float4 a01 = *(const float4*)(xp + 4);
        float4 a10 = *(const float4*)(xp + 32);
        float4 a11 = *(const float4*)(xp + 36);
        bf16x8 a0, a1;
        a0[0] = f2bf(a00.x); a0[1] = f2bf(a00.y); a0[2] = f2bf(a00.z); a0[3] = f2bf(a00.w);
        a0[4] = f2bf(a01.x); a0[5] = f2bf(a01.y); a0[6] = f2bf(a01.z); a0[7] = f2bf(a01.w);
        a1[0] = f2bf(a10.x); a1[1] = f2bf(a10.y); a1[2] = f2bf(a10.z); a1[3] = f2bf(a10.w);
        a1[4] = f2bf(a11.x); a1[5] = f2bf(a11.y); a1[6] = f2bf(a11.z); a1[7] = f2bf(a11.w);

        f32x4 acc[4];
        #pragma unroll
        for (int ct = 0; ct < 4; ++ct) {
            acc[ct] = (f32x4){0.f, 0.f, 0.f, 0.f};
            acc[ct] = __builtin_amdgcn_mfma_f32_16x16x32_bf16(a0, bfrag[ct][0], acc[ct], 0, 0, 0);
            acc[ct] = __builtin_amdgcn_mfma_f32_16x16x32_bf16(a1, bfrag[ct][1], acc[ct], 0, 0, 0);
        }

        #pragma unroll
        for (int reg = 0; reg < 4; ++reg) {
            int nr = n0 + kg * 4 + reg;
            if (nr < N) {
                float dn = dis[nr];
                #pragma unroll
                for (int ct = 0; ct < 4; ++ct) {
                    z[(size_t)nr * FD + ct * 16 + r16] =
                        (unsigned short)f2bf(acc[ct][reg] * dn);
                }
            }
        }
    }
}

// ---------------- pure gather over bf16 z, 4 edges per vmem instruction ----------------
// One wave per dst node. lane = g*16 + fl: g = edge slot (0..3), fl = feature quad.
// Each lane loads ushort4 (8 B) of row bucket[j+g] -> one instruction covers 4 edges.
// Reduction over g via 2 shfl_xor steps; g==0 lanes add self-loop and store float4.
__global__ __launch_bounds__(256) void gather_z_kernel(
        const unsigned short* __restrict__ z, const int* __restrict__ offs,
        const int* __restrict__ bsums, const int* __restrict__ degi,
        const int* __restrict__ bucket, const float* __restrict__ dis,
        float* __restrict__ out, int N) {
    int wave = threadIdx.x >> 6;
    int lane = threadIdx.x & 63;
    int n = blockIdx.x * 4 + wave;
    if (n >= N) return;

    int g  = lane >> 4;    // edge slot 0..3
    int fl = lane & 15;    // feature quad: features 4*fl .. 4*fl+3
    unsigned fo = (unsigned)(fl << 2);   // element offset within row

    int j   = offs[n] + bsums[n >> 11];
    int end = j + degi[n];

    float4 acc = make_float4(0.f, 0.f, 0.f, 0.f);

    // main: 8 edges per iteration (2 x 4-wide)
    for (; j + 8 <= end; j += 8) {
        int4 b0 = *(const int4*)&bucket[j];       // uniform -> broadcast
        int4 b1 = *(const int4*)&bucket[j + 4];
        int s0 = (g & 2) ? ((g & 1) ? b0.w : b0.z) : ((g & 1) ? b0.y : b0.x);
        int s1 = (g & 2) ? ((g & 1) ? b1.w : b1.z) : ((g & 1) ? b1.y : b1.x);
        u16x4 r0 = *(const u16x4*)(z + (((unsigned)s0 << 6) | fo));
        u16x4 r1 = *(const u16x4*)(z + (((unsigned)s1 << 6) | fo));
        acc.x += bf2f(r0[0]) + bf2f(r1[0]);
        acc.y += bf2f(r0[1]) + bf2f(r1[1]);
        acc.z += bf2f(r0[2]) + bf2f(r1[2]);
        acc.w += bf2f(r0[3]) + bf2f(r1[3]);
    }
    // 4-wide
    for (; j + 4 <= end; j += 4) {
        int4 b = *(const int4*)&bucket[j];
        int s = (g & 2) ? ((g & 1) ? b.w : b.z) : ((g & 1) ? b.y : b.x);
        u16x4 r = *(const u16x4*)(z + (((unsigned)s << 6) | fo));
        acc.x += bf2f(r[0]);
        acc.y += bf2f(r[1]);
        acc.z += bf2f(r[2]);
        acc.w += bf2f(r[3]);
    }
    // tail 1..3: lanes with g < rem handle edge j+g
    if (j < end) {
        int rem = end - j;
        if (g < rem) {
            int s = bucket[j + g];
            u16x4 r = *(const u16x4*)(z + (((unsigned)s << 6) | fo));
            acc.x += bf2f(r[0]);
            acc.y += bf2f(r[1]);
            acc.z += bf2f(r[2]);
            acc.w += bf2f(r[3]);
        }
    }
    // self-loop on g==0 lanes (before reduction; other slots contribute 0)
    if (g == 0) {
        u16x4 r = *(const u16x4*)(z + (((unsigned)n << 6) | fo));
        acc.x += bf2f(r[0]);
        acc.y += bf2f(r[1]);
        acc.z += bf2f(r[2]);
        acc.w += bf2f(r[3]);
    }

    // reduce over edge slots: lanes fl, fl+16, fl+32, fl+48
    acc.x += __shfl_xor(acc.x, 32, 64);
    acc.y += __shfl_xor(acc.y, 32, 64);
    acc.z += __shfl_xor(acc.z, 32, 64);
    acc.w += __shfl_xor(acc.w, 32, 64);
    acc.x += __shfl_xor(acc.x, 16, 64);
    acc.y += __shfl_xor(acc.y, 16, 64);
    acc.z += __shfl_xor(acc.z, 16, 64);
    acc.w += __shfl_xor(acc.w, 16, 64);

    if (g == 0) {
        float dn = dis[n];
        float4 o = make_float4(acc.x * dn, acc.y * dn, acc.z * dn, acc.w * dn);
        *(float4*)(out + (size_t)n * FD + fo) = o;
    }
}

// ---------------- fallback (ws too small): round-4 fused path ----------------
__global__ void deg_kernel(const int* __restrict__ dst, int* __restrict__ degi, int E) {
    int i = blockIdx.x * blockDim.x + threadIdx.x;
    int stride = gridDim.x * blockDim.x;
    for (; i < E; i += stride) {
        atomicAdd(&degi[dst[i]], 1);
    }
}

__global__ void fill_kernel(const int* __restrict__ src, const int* __restrict__ dst,
                            const int* __restrict__ offs, int* __restrict__ cursor,
                            int* __restrict__ bucket, int E) {
    int i = blockIdx.x * blockDim.x + threadIdx.x;
    int stride = gridDim.x * blockDim.x;
    for (; i < E; i += stride) {
        int d = dst[i];
        int p = atomicAdd(&cursor[d], 1);
        bucket[offs[d] + p] = src[i];
    }
}

__global__ __launch_bounds__(256) void gather_linear_kernel(
        const float* __restrict__ x, const int* __restrict__ offs,
        const int* __restrict__ degi, const int* __restrict__ bucket,
        const float* __restrict__ dis, const float* __restrict__ W,
        float* __restrict__ out, int N) {
    __shared__ float Wt[FD][FD + 1];
    __shared__ float rows[4][FD];

    for (int t = threadIdx.x; t < FD * FD; t += 256) {
        Wt[t & 63][t >> 6] = W[t];
    }
    __syncthreads();

    int wave = threadIdx.x >> 6;
    int lane = threadIdx.x & 63;
    int n = blockIdx.x * 4 + wave;

    if (n < N) {
        int j   = offs[n];
        int end = j + degi[n];
        float acc = 0.0f;
        for (; j + 3 < end; j += 4) {
            int s0 = bucket[j], s1 = bucket[j + 1], s2 = bucket[j + 2], s3 = bucket[j + 3];
            float d0 = dis[s0], d1 = dis[s1], d2 = dis[s2], d3 = dis[s3];
            float v0 = x[(size_t)s0 * FD + lane];
            float v1 = x[(size_t)s1 * FD + lane];
            float v2 = x[(size_t)s2 * FD + lane];
            float v3 = x[(size_t)s3 * FD + lane];
            acc += v0 * d0 + v1 * d1 + v2 * d2 + v3 * d3;
        }
        for (; j < end; ++j) {
            int s = bucket[j];
            acc += x[(size_t)s * FD + lane] * dis[s];
        }
        float dn = dis[n];
        rows[wave][lane] = (acc + x[(size_t)n * FD + lane] * dn) * dn;
    }
    if (n < N) {
        float o = 0.0f;
        #pragma unroll
        for (int i = 0; i < FD; i += 4) {
            float4 r = *(const float4*)&rows[wave][i];
            o += r.x * Wt[i + 0][lane]
               + r.y * Wt[i + 1][lane]
               + r.z * Wt[i + 2][lane]
               + r.w * Wt[i + 3][lane];
        }
        out[(size_t)n * FD + lane] = o;
    }
}

extern "C" void kernel_launch(void* const* d_in, const int* in_sizes, int n_in,
                              void* d_out, int out_size, void* d_ws, size_t ws_size,
                              hipStream_t stream) {
    const float* x  = (const float*)d_in[0];
    const int*   ei = (const int*)d_in[1];   // [2, E]: src row then dst row
    const float* W  = (const float*)d_in[2];

    const int N = in_sizes[0] / FD;
    const int E = in_sizes[1] / 2;
    const int* src = ei;
    const int* dst = ei + E;

    float* out = (float*)d_out;
    const int nb = (N + SCAN_ELEMS - 1) / SCAN_ELEMS;

    // Full layout: degi[N] | dis[N] | offs[N] | bsums[1024] | bucket[E] | pos[E]u16 | z[N*FD]bf16
    size_t posB = (((size_t)E * 2) + 3) & ~(size_t)3;
    size_t need_full = ((size_t)N * 3 + 1024 + (size_t)E) * 4 + posB + (size_t)N * FD * 2;

    if (ws_size >= need_full) {
        char* ws = (char*)d_ws;
        int*   degi   = (int*)ws;    ws += (size_t)N * 4;
        float* dis    = (float*)ws;  ws += (size_t)N * 4;
        int*   offs   = (int*)ws;    ws += (size_t)N * 4;
        int*   bsums  = (int*)ws;    ws += 1024 * 4;
        int*   bucket = (int*)ws;    ws += (size_t)E * 4;
        unsigned short* pos = (unsigned short*)ws;  ws += posB;
        unsigned short* z   = (unsigned short*)ws;

        hipMemsetAsync(degi, 0, (size_t)N * 4, stream);
        degpos_kernel<<<2048, 256, 0, stream>>>(dst, degi, pos, E);
        scan1_kernel<<<nb, 256, 0, stream>>>(degi, offs, bsums, dis, N);
        scan2_kernel<<<1, 256, 0, stream>>>(bsums, nb);
        z_mfma_kernel<<<512, 256, 0, stream>>>(x, dis, W, z, N);
        fill_pos_kernel<<<2048, 256, 0, stream>>>(src, dst, offs, bsums, pos, bucket, E);
        gather_z_kernel<<<(N + 3) / 4, 256, 0, stream>>>(z, offs, bsums, degi, bucket, dis, out, N);
    } else {
        // Fallback (round-4 structure): degi | dis | offs | cursor | bsums | bucket
        char* ws = (char*)d_ws;
        int*   degi   = (int*)ws;    ws += (size_t)N * 4;
        float* dis    = (float*)ws;  ws += (size_t)N * 4;
        int*   offs   = (int*)ws;    ws += (size_t)N * 4;
        int*   cursor = (int*)ws;    ws += (size_t)N * 4;
        int*   bsums  = (int*)ws;    ws += 1024 * 4;
        int*   bucket = (int*)ws;

        hipMemsetAsync(degi,   0, (size_t)N * 4, stream);
        hipMemsetAsync(cursor, 0, (size_t)N * 4, stream);
        deg_kernel<<<2048, 256, 0, stream>>>(dst, degi, E);
        scan1_kernel<<<nb, 256, 0, stream>>>(degi, offs, bsums, dis, N);
        scan2_kernel<<<1, 256, 0, stream>>>(bsums, nb);
        scan3_kernel<<<(N + 255) / 256, 256, 0, stream>>>(offs, bsums, N);
        fill_kernel<<<2048, 256, 0, stream>>>(src, dst, offs, cursor, bucket, E);
        gather_linear_kernel<<<(N + 3) / 4, 256, 0, stream>>>(
            x, offs, degi, bucket, dis, W, out, N);
    }
}